// Round 8
// baseline (4758.883 us; speedup 1.0000x reference)
//
#include <hip/hip_runtime.h>
#include <hip/hip_bf16.h>

// Problem constants
#define B_  2048   // batch
#define T_  32     // T_SRC == T_TGT
#define D_  512    // model dim
#define G_  2048   // 4*D
#define VT_ 80     // D_TGT
#define BD  (B_ * D_)          // elems per state plane
#define LWE ((size_t)G_ * D_)  // per-layer weight elems

typedef _Float16 half8 __attribute__((ext_vector_type(8)));
typedef _Float16 half4_t __attribute__((ext_vector_type(4)));
typedef float    f32x4 __attribute__((ext_vector_type(4)));

static __device__ __forceinline__ float sigm(float x) {
    return 1.0f / (1.0f + expf(-x));
}

// ---------------------------------------------------------------------------
__global__ void zero_ws(int4* __restrict__ p, int n) {
    int i = blockIdx.x * blockDim.x + threadIdx.x;
    if (i < n) p[i] = int4{0, 0, 0, 0};
}
__global__ void init_pred(const int* __restrict__ tgt, int* __restrict__ pred) {
    int i = blockIdx.x * blockDim.x + threadIdx.x;
    if (i < B_) pred[i] = tgt[i * T_];
}

// ---------------------------------------------------------------------------
// Split 6 weight matrices (fp32 GxD) into fp16 hi/lo planes, gate-interleaved
// column order n' = d*4 + g, MFMA B-frag tile order:
// tile(NI=n'>>4, KC=k>>5), lane = (n'&15) | (((k>>3)&3)<<4), elem = k&7.
// ---------------------------------------------------------------------------
__global__ void split_weights(const float* __restrict__ s0, const float* __restrict__ s1,
                              const float* __restrict__ s2, const float* __restrict__ s3,
                              const float* __restrict__ s4, const float* __restrict__ s5,
                              _Float16* __restrict__ Wbase) {
    int g = blockIdx.x * blockDim.x + threadIdx.x;   // 6 * 2048 * 64
    int mat = g >> 17;
    int rem = g & 131071;
    int np  = rem >> 6;
    int kq  = rem & 63;                               // k-octet
    const float* src = (mat == 0) ? s0 : (mat == 1) ? s1 : (mat == 2) ? s2
                     : (mat == 3) ? s3 : (mat == 4) ? s4 : s5;
    int n = (np & 3) * D_ + (np >> 2);
    const float* sp = src + (size_t)n * D_ + kq * 8;
    float4 v0 = ((const float4*)sp)[0], v1 = ((const float4*)sp)[1];
    float x[8] = {v0.x, v0.y, v0.z, v0.w, v1.x, v1.y, v1.z, v1.w};
    _Float16 hi[8], lo[8];
    #pragma unroll
    for (int u = 0; u < 8; ++u) {
        hi[u] = (_Float16)x[u];
        lo[u] = (_Float16)(x[u] - (float)hi[u]);
    }
    int tile = (np >> 4) * 16 + (kq >> 2);
    int lane = (np & 15) | ((kq & 3) << 4);
    size_t e = (size_t)tile * 512 + (size_t)lane * 8;
    _Float16* Whi = Wbase + (size_t)mat * (2 * LWE);
    _Float16* Wlo = Whi + LWE;
    *(half8*)(Whi + e) = *(half8*)hi;
    *(half8*)(Wlo + e) = *(half8*)lo;
}

// ---------------------------------------------------------------------------
// post_W (80 x 512 fp32) -> hi/lo fp16 B-frag tiles, n' = v.
// ---------------------------------------------------------------------------
__global__ void split_postW(const float* __restrict__ pw,
                            _Float16* __restrict__ Ph, _Float16* __restrict__ Pl) {
    int g = blockIdx.x * blockDim.x + threadIdx.x;   // 80*64 = 5120
    if (g >= VT_ * 64) return;
    int v = g >> 6, kq = g & 63;
    const float* sp = pw + (size_t)v * D_ + kq * 8;
    float4 v0 = ((const float4*)sp)[0], v1 = ((const float4*)sp)[1];
    float x[8] = {v0.x, v0.y, v0.z, v0.w, v1.x, v1.y, v1.z, v1.w};
    _Float16 hi[8], lo[8];
    #pragma unroll
    for (int u = 0; u < 8; ++u) {
        hi[u] = (_Float16)x[u];
        lo[u] = (_Float16)(x[u] - (float)hi[u]);
    }
    int tile = (v >> 4) * 16 + (kq >> 2);
    int lane = (v & 15) | ((kq & 3) << 4);
    size_t e = (size_t)tile * 512 + (size_t)lane * 8;
    *(half8*)(Ph + e) = *(half8*)hi;
    *(half8*)(Pl + e) = *(half8*)lo;
}

// ---------------------------------------------------------------------------
__global__ void perm_bias(const float* __restrict__ ebih, const float* __restrict__ ebhh,
                          const float* __restrict__ dbih, const float* __restrict__ dbhh,
                          float* __restrict__ biasP) {
    int i = blockIdx.x * blockDim.x + threadIdx.x;   // 0..8191
    int cfg = i >> 11, np = i & 2047;
    int n = (np & 3) * D_ + (np >> 2);
    const float* bi = ((cfg < 2) ? ebih : dbih) + (cfg & 1) * G_;
    const float* bh = ((cfg < 2) ? ebhh : dbhh) + (cfg & 1) * G_;
    biasP[cfg * G_ + np] = bi[n] + bh[n];
}

// ---------------------------------------------------------------------------
// Exact fp32 input projections, permuted n'. 18 row-groups of 10 rows.
// ---------------------------------------------------------------------------
__global__ __launch_bounds__(256) void compute_P(
    const float* __restrict__ enc_emb, const float* __restrict__ dec_emb,
    const float* __restrict__ encW0,   const float* __restrict__ decW0,
    float* __restrict__ P) {
    __shared__ float es[10][D_];
    __shared__ float part[4][64][10];
    int by = blockIdx.y;
    bool enc = (by < 10);
    int r0 = enc ? by * 10 : 100 + (by - 10) * 10;
    int s0 = enc ? by * 10 : (by - 10) * 10;
    const float* emb = enc ? enc_emb : dec_emb;
    const float* W   = enc ? encW0 : decW0;
    int tid = threadIdx.x;
    #pragma unroll
    for (int it = 0; it < 5; ++it) {
        int i4 = it * 256 + tid;
        int rr = i4 >> 7, cc = i4 & 127;
        ((float4*)es[rr])[cc] = ((const float4*)(emb + (size_t)(s0 + rr) * D_))[cc];
    }
    __syncthreads();
    int o   = tid & 63;
    int seg = tid >> 6;
    int np = blockIdx.x * 64 + o;
    int n = (np & 3) * D_ + (np >> 2);
    const float* wr = W + (size_t)n * D_ + seg * 128;
    float acc[10];
    #pragma unroll
    for (int rr = 0; rr < 10; ++rr) acc[rr] = 0.f;
    for (int k = 0; k < 128; k += 4) {
        float4 w4 = *(const float4*)(wr + k);
        int kb = seg * 128 + k;
        #pragma unroll
        for (int rr = 0; rr < 10; ++rr)
            acc[rr] += es[rr][kb] * w4.x + es[rr][kb+1] * w4.y
                     + es[rr][kb+2] * w4.z + es[rr][kb+3] * w4.w;
    }
    #pragma unroll
    for (int rr = 0; rr < 10; ++rr) part[seg][o][rr] = acc[rr];
    __syncthreads();
    for (int i = tid; i < 640; i += 256) {
        int o2 = i & 63, rr = i >> 6;
        P[(size_t)(r0 + rr) * G_ + blockIdx.x * 64 + o2] =
            (part[0][o2][rr] + part[1][o2][rr]) + (part[2][o2][rr] + part[3][o2][rr]);
    }
}

// ---------------------------------------------------------------------------
// chunk loaders / MFMA
// ---------------------------------------------------------------------------
static __device__ __forceinline__ void load_chunk(
    const _Float16* __restrict__ Ah, const _Float16* __restrict__ Al,
    const _Float16* __restrict__ Wh, const _Float16* __restrict__ Wl,
    int afr, int wfr, int kc, int lane, half8* A8, half8* B8) {
    size_t lo8 = (size_t)lane * 8;
    #pragma unroll
    for (int i = 0; i < 4; ++i) {
        size_t off = (((size_t)(afr + i) * 16 + kc) << 9) + lo8;
        A8[i]     = *(const half8*)(Ah + off);
        A8[4 + i] = *(const half8*)(Al + off);
    }
    #pragma unroll
    for (int j = 0; j < 4; ++j) {
        size_t off = (((size_t)(wfr + j) * 16 + kc) << 9) + lo8;
        B8[j]     = *(const half8*)(Wh + off);
        B8[4 + j] = *(const half8*)(Wl + off);
    }
}
static __device__ __forceinline__ void mfma_chunk(
    const half8* A8, const half8* B8, f32x4 acc[4][4]) {
    #pragma unroll
    for (int i = 0; i < 4; ++i)
        #pragma unroll
        for (int j = 0; j < 4; ++j) {
            acc[i][j] = __builtin_amdgcn_mfma_f32_16x16x32_f16(A8[i], B8[j], acc[i][j], 0, 0, 0);
            acc[i][j] = __builtin_amdgcn_mfma_f32_16x16x32_f16(A8[i], B8[4 + j], acc[i][j], 0, 0, 0);
            acc[i][j] = __builtin_amdgcn_mfma_f32_16x16x32_f16(A8[4 + i], B8[j], acc[i][j], 0, 0, 0);
        }
}

// ---------------------------------------------------------------------------
// MFMA LSTM cell. Block = 512 thr = 8 waves = 2 m-waves x 4 K-groups.
// BM=128, BN'=64; grid (32, 16, z) = 512 blocks/job = 2 blocks/CU
// (16 waves/CU). Wave tile 64m x 64n', fp16 hi/lo 3-product. Barrier-free
// register double-buffered K-loop; 4-group reduction in the LDS epilogue.
// nph=1: single phase (h@Whh), K split 4 ways (4 chunks each).
// nph=2: two phases (x@Wih, h@Whh), each split 2 ways (8 chunks each).
// ---------------------------------------------------------------------------
struct CellJob {
    const _Float16 *a0h, *a0l, *w0h, *w0l;
    const _Float16 *a1h, *a1l, *w1h, *w1l;
    int nph;
    const float *biasP;
    const float *P;
    const int  *idx;
    int idx_stride, emb_rows;
    float *c_io;
    _Float16 *hh_out, *hl_out;
};

__global__ __launch_bounds__(512, 2) void lstm_cell_mfma(CellJob J0, CellJob J1) {
    const CellJob J = (blockIdx.z == 0) ? J0 : J1;
    __shared__ float gf[128][68];
    const int tid  = threadIdx.x;
    const int w    = tid >> 6;
    const int lane = tid & 63;
    const int g    = w >> 1;        // K-group 0..3
    const int mw   = w & 1;         // m-wave within group
    const int bx   = blockIdx.x;
    const int m0   = blockIdx.y * 128;

    int ph, kclo, kchi;
    if (J.nph == 2) { ph = g >> 1; kclo = (g & 1) * 8; kchi = kclo + 8; }
    else            { ph = 0;      kclo = g * 4;       kchi = kclo + 4; }

    const _Float16* Ah = ph ? J.a1h : J.a0h;
    const _Float16* Al = ph ? J.a1l : J.a0l;
    const _Float16* Wh = ph ? J.w1h : J.w0h;
    const _Float16* Wl = ph ? J.w1l : J.w0l;

    const int afr = (m0 >> 4) + mw * 4;
    const int wfr = bx * 4;

    f32x4 acc[4][4];
    #pragma unroll
    for (int i = 0; i < 4; ++i)
        #pragma unroll
        for (int j = 0; j < 4; ++j) acc[i][j] = f32x4{0.f, 0.f, 0.f, 0.f};

    half8 A0[8], B0[8], A1[8], B1[8];
    load_chunk(Ah, Al, Wh, Wl, afr, wfr, kclo, lane, A0, B0);
    for (int kc = kclo; kc < kchi; kc += 2) {
        load_chunk(Ah, Al, Wh, Wl, afr, wfr, kc + 1, lane, A1, B1);
        mfma_chunk(A0, B0, acc);
        if (kc + 2 < kchi)
            load_chunk(Ah, Al, Wh, Wl, afr, wfr, kc + 2, lane, A0, B0);
        mfma_chunk(A1, B1, acc);
    }

    // ---- epilogue: group-0 writes, groups 1..3 add (serial LDS reduce) ----
    const int rbase = (lane >> 4) << 2;   // C/D: row = quad*4 + reg
    const int cbase = lane & 15;          //      col = lane&15
    if (g == 0) {
        #pragma unroll
        for (int i = 0; i < 4; ++i) {
            int mrow = mw * 64 + i * 16 + rbase;
            #pragma unroll
            for (int j = 0; j < 4; ++j) {
                int nc = j * 16 + cbase;
                #pragma unroll
                for (int r = 0; r < 4; ++r)
                    gf[mrow + r][nc] = acc[i][j][r];
            }
        }
    }
    __syncthreads();
    #pragma unroll
    for (int gg = 1; gg < 4; ++gg) {
        if (g == gg) {
            #pragma unroll
            for (int i = 0; i < 4; ++i) {
                int mrow = mw * 64 + i * 16 + rbase;
                #pragma unroll
                for (int j = 0; j < 4; ++j) {
                    int nc = j * 16 + cbase;
                    #pragma unroll
                    for (int r = 0; r < 4; ++r)
                        gf[mrow + r][nc] += acc[i][j][r];
                }
            }
        }
        __syncthreads();
    }
    // ---- pointwise: 512 threads x 4 d-values over 128 rows ----
    {
        int mr = tid >> 2, q = tid & 3;
        int mg = m0 + mr;
        const float4* brow = (const float4*)(J.biasP + (bx << 6));
        const float4* Pr = nullptr;
        if (J.P) {
            int s = J.idx[mg * J.idx_stride];
            s = min(max(s, 0), J.emb_rows - 1);
            Pr = (const float4*)(J.P + (size_t)s * G_ + (bx << 6));
        }
        float* crow = J.c_io + (size_t)mg * D_ + (bx << 4) + (q << 2);
        float4 cv = *(float4*)crow;
        _Float16 hh4[4], hl4[4];
        #pragma unroll
        for (int e = 0; e < 4; ++e) {
            int dl = (q << 2) + e;
            float4 g4 = *(float4*)&gf[mr][dl << 2];
            float4 b4 = brow[dl];
            float gi = g4.x + b4.x, gF = g4.y + b4.y;
            float gg = g4.z + b4.z, go = g4.w + b4.w;
            if (Pr) {
                float4 p4 = Pr[dl];
                gi += p4.x; gF += p4.y; gg += p4.z; go += p4.w;
            }
            float cc = (&cv.x)[e];
            float cn = sigm(gF) * cc + sigm(gi) * tanhf(gg);
            float hn = sigm(go) * tanhf(cn);
            (&cv.x)[e] = cn;
            _Float16 hH = (_Float16)hn;
            hh4[e] = hH;
            hl4[e] = (_Float16)(hn - (float)hH);
        }
        *(float4*)crow = cv;
        int kk = (bx << 4) + (q << 2);
        size_t hoff = ((size_t)((mg >> 4) * 16 + (kk >> 5)) << 9)
                    + (size_t)((mg & 15) | (((kk >> 3) & 3) << 4)) * 8
                    + ((q & 1) << 2);
        *(half4_t*)(J.hh_out + hoff) = *(half4_t*)hh4;
        *(half4_t*)(J.hl_out + hoff) = *(half4_t*)hl4;
    }
}

// ---------------------------------------------------------------------------
// MFMA logits + argmax. Grid 32 blocks x 128 thr (2 waves = 2 K-halves).
// ---------------------------------------------------------------------------
__global__ __launch_bounds__(128) void logits_mfma(
    const _Float16* __restrict__ Ah, const _Float16* __restrict__ Al,
    const _Float16* __restrict__ Bh, const _Float16* __restrict__ Bl,
    const float* __restrict__ postb, float* __restrict__ out,
    int t, int* __restrict__ pred) {
    __shared__ float gf2[64][85];
    __shared__ float pb[VT_];
    const int tid = threadIdx.x;
    const int w = tid >> 6;
    const int lane = tid & 63;
    const int m0 = blockIdx.x * 64;
    const int afr = blockIdx.x * 4;

    f32x4 acc[4][5];
    #pragma unroll
    for (int i = 0; i < 4; ++i)
        #pragma unroll
        for (int j = 0; j < 5; ++j) acc[i][j] = f32x4{0.f, 0.f, 0.f, 0.f};

    size_t lo8 = (size_t)lane * 8;
    for (int kc = w * 8; kc < w * 8 + 8; ++kc) {
        half8 A8[8], Bh8[5], Bl8[5];
        #pragma unroll
        for (int i = 0; i < 4; ++i) {
            size_t off = (((size_t)(afr + i) * 16 + kc) << 9) + lo8;
            A8[i]     = *(const half8*)(Ah + off);
            A8[4 + i] = *(const half8*)(Al + off);
        }
        #pragma unroll
        for (int j = 0; j < 5; ++j) {
            size_t off = (((size_t)(j * 16 + kc)) << 9) + lo8;
            Bh8[j] = *(const half8*)(Bh + off);
            Bl8[j] = *(const half8*)(Bl + off);
        }
        #pragma unroll
        for (int i = 0; i < 4; ++i)
            #pragma unroll
            for (int j = 0; j < 5; ++j) {
                acc[i][j] = __builtin_amdgcn_mfma_f32_16x16x32_f16(A8[i], Bh8[j], acc[i][j], 0, 0, 0);
                acc[i][j] = __builtin_amdgcn_mfma_f32_16x16x32_f16(A8[i], Bl8[j], acc[i][j], 0, 0, 0);
                acc[i][j] = __builtin_amdgcn_mfma_f32_16x16x32_f16(A8[4 + i], Bh8[j], acc[i][j], 0, 0, 0);
            }
    }

    if (tid < VT_) pb[tid] = postb[tid];
    const int quad = lane >> 4, c = lane & 15;
    if (w == 0) {
        #pragma unroll
        for (int i = 0; i < 4; ++i)
            #pragma unroll
            for (int j = 0; j < 5; ++j)
                #pragma unroll
                for (int r = 0; r < 4; ++r)
                    gf2[i * 16 + quad * 4 + r][j * 16 + c] = acc[i][j][r];
    }
    __syncthreads();
    if (w == 1) {
        #pragma unroll
        for (int i = 0; i < 4; ++i)
            #pragma unroll
            for (int j = 0; j < 5; ++j)
                #pragma unroll
                for (int r = 0; r < 4; ++r)
                    gf2[i * 16 + quad * 4 + r][j * 16 + c] += acc[i][j][r];
    }
    __syncthreads();
    if (tid < 64) {
        int r = tid;
        float best = -3.4e38f; int bi = 0;
        #pragma unroll
        for (int v = 0; v < VT_; ++v) {
            float x = gf2[r][v] + pb[v];
            if (x > best) { best = x; bi = v; }
        }
        pred[m0 + r] = bi;
        float* orow = out + (size_t)(m0 + r) * (T_ * VT_) + (size_t)t * VT_;
        #pragma unroll
        for (int v4 = 0; v4 < VT_ / 4; ++v4) {
            float4 g4 = *(float4*)&gf2[r][v4 * 4];
            float4 b4 = *(float4*)&pb[v4 * 4];
            float4 o4 = {g4.x + b4.x, g4.y + b4.y, g4.z + b4.z, g4.w + b4.w};
            *(float4*)(orow + v4 * 4) = o4;
        }
    }
}

// ---------------------------------------------------------------------------
extern "C" void kernel_launch(void* const* d_in, const int* in_sizes, int n_in,
                              void* d_out, int out_size, void* d_ws, size_t ws_size,
                              hipStream_t stream) {
    (void)in_sizes; (void)n_in; (void)out_size; (void)ws_size;

    const int*   src     = (const int*)d_in[0];
    const int*   tgt     = (const int*)d_in[1];
    const float* enc_emb = (const float*)d_in[2];
    const float* dec_emb = (const float*)d_in[3];
    const float* enc_Wih = (const float*)d_in[4];
    const float* enc_Whh = (const float*)d_in[5];
    const float* enc_bih = (const float*)d_in[6];
    const float* enc_bhh = (const float*)d_in[7];
    const float* dec_Wih = (const float*)d_in[8];
    const float* dec_Whh = (const float*)d_in[9];
    const float* dec_bih = (const float*)d_in[10];
    const float* dec_bhh = (const float*)d_in[11];
    const float* post_W  = (const float*)d_in[12];
    const float* post_b  = (const float*)d_in[13];

    // ---- ws layout (~50 MiB) ----
    char* wsb = (char*)d_ws;
    int*   pred  = (int*)wsb;                                   // 16 KB
    float* biasB = (float*)(wsb + 16384);                       // 32 KB
    float* Ptab  = (float*)(wsb + 16384 + 32768);               // 1.41 MiB
    char*  zbase = wsb + 16384 + 32768 + 180 * G_ * 4;          // zero-span
    float* C0 = (float*)zbase;
    float* C1 = C0 + BD;
    _Float16* Hh00 = (_Float16*)(C1 + BD);
    _Float16* Hh10 = Hh00 + BD;
    _Float16* Hl00 = Hh10 + BD;
    _Float16* Hl10 = Hl00 + BD;
    _Float16* Hh01 = Hl10 + BD;   // not zeroed (fully written before read)
    _Float16* Hh11 = Hh01 + BD;
    _Float16* Hl01 = Hh11 + BD;
    _Float16* Hl11 = Hl01 + BD;
    _Float16* Wb   = Hl11 + BD;                      // 6 split matrices, 24 MiB
    _Float16* PwH  = Wb + 6 * 2 * LWE;               // post_W hi frag tiles
    _Float16* PwL  = PwH + (size_t)VT_ * D_;         // post_W lo frag tiles

    _Float16* Hhi[2][2] = { { Hh00, Hh01 }, { Hh10, Hh11 } };
    _Float16* Hlo[2][2] = { { Hl00, Hl01 }, { Hl10, Hl11 } };
    float*    Cp[2]     = { C0, C1 };
    auto WP = [&](int m, int pl) { return Wb + (size_t)m * (2 * LWE) + (size_t)pl * LWE; };

    float* out = (float*)d_out;

    // ---- precompute ----
    zero_ws<<<4096, 256, 0, stream>>>((int4*)zbase, (16 * 1024 * 1024) / 16);
    init_pred<<<8, 256, 0, stream>>>(tgt, pred);
    split_weights<<<3072, 256, 0, stream>>>(
        enc_Whh, enc_Wih + LWE, enc_Whh + LWE,
        dec_Whh, dec_Wih + LWE, dec_Whh + LWE, Wb);
    split_postW<<<20, 256, 0, stream>>>(post_W, PwH, PwL);
    perm_bias<<<32, 256, 0, stream>>>(enc_bih, enc_bhh, dec_bih, dec_bhh, biasB);
    {
        dim3 gP(32, 18);
        compute_P<<<gP, 256, 0, stream>>>(enc_emb, dec_emb, enc_Wih, dec_Wih, Ptab);
    }

    dim3 grid1(G_ / 64, B_ / 128, 1);    // single job, 512 blocks
    dim3 grid2(G_ / 64, B_ / 128, 2);    // paired jobs, 1024 blocks
    int c0 = 0, c1 = 0;

    auto mkL0 = [&](bool enc, const int* ix, int stride, int rows) {
        int m = enc ? 0 : 3;
        CellJob j;
        j.a0h = Hhi[0][c0]; j.a0l = Hlo[0][c0];
        j.w0h = WP(m, 0);   j.w0l = WP(m, 1);
        j.a1h = nullptr; j.a1l = nullptr; j.w1h = nullptr; j.w1l = nullptr;
        j.nph = 1;
        j.biasP = biasB + (enc ? 0 : 2) * G_;
        j.P = enc ? Ptab : Ptab + (size_t)100 * G_;
        j.idx = ix; j.idx_stride = stride; j.emb_rows = rows;
        j.c_io = Cp[0];
        j.hh_out = Hhi[0][c0 ^ 1]; j.hl_out = Hlo[0][c0 ^ 1];
        return j;
    };
    auto mkL1 = [&](bool enc) {
        int mi = enc ? 1 : 4, mh = enc ? 2 : 5;
        CellJob j;
        j.a0h = Hhi[0][c0]; j.a0l = Hlo[0][c0];
        j.w0h = WP(mi, 0);  j.w0l = WP(mi, 1);
        j.a1h = Hhi[1][c1]; j.a1l = Hlo[1][c1];
        j.w1h = WP(mh, 0);  j.w1l = WP(mh, 1);
        j.nph = 2;
        j.biasP = biasB + (enc ? 1 : 3) * G_;
        j.P = nullptr; j.idx = nullptr; j.idx_stride = 0; j.emb_rows = 0;
        j.c_io = Cp[1];
        j.hh_out = Hhi[1][c1 ^ 1]; j.hl_out = Hlo[1][c1 ^ 1];
        return j;
    };

    // -------- encoder (layer1(t) paired with layer0(t+1)) --------
    {
        CellJob j0 = mkL0(true, src + 0, T_, 100);
        lstm_cell_mfma<<<grid1, 512, 0, stream>>>(j0, j0);
        c0 ^= 1;
        for (int t = 0; t < T_ - 1; ++t) {
            CellJob jA = mkL1(true);                       // layer1(t)
            CellJob jB = mkL0(true, src + t + 1, T_, 100); // layer0(t+1)
            lstm_cell_mfma<<<grid2, 512, 0, stream>>>(jA, jB);
            c1 ^= 1; c0 ^= 1;
        }
        CellJob jZ = mkL1(true);
        lstm_cell_mfma<<<grid1, 512, 0, stream>>>(jZ, jZ);
        c1 ^= 1;
    }

    // -------- decoder (greedy feedback, serial) --------
    for (int t = 0; t < T_; ++t) {
        CellJob j0 = mkL0(false, pred, 1, VT_);
        lstm_cell_mfma<<<grid1, 512, 0, stream>>>(j0, j0);
        c0 ^= 1;
        CellJob j1 = mkL1(false);
        lstm_cell_mfma<<<grid1, 512, 0, stream>>>(j1, j1);
        c1 ^= 1;
        logits_mfma<<<32, 128, 0, stream>>>(
            Hhi[1][c1], Hlo[1][c1], PwH, PwL, post_b, out, t, pred);
    }
}

// Round 9
// 3978.048 us; speedup vs baseline: 1.1963x; 1.1963x over previous
//
#include <hip/hip_runtime.h>
#include <hip/hip_bf16.h>

// Problem constants
#define B_  2048   // batch
#define T_  32     // T_SRC == T_TGT
#define D_  512    // model dim
#define G_  2048   // 4*D
#define VT_ 80     // D_TGT
#define BD  (B_ * D_)          // elems per state plane
#define LWE ((size_t)G_ * D_)  // per-layer weight elems

typedef _Float16 half8 __attribute__((ext_vector_type(8)));
typedef _Float16 half4_t __attribute__((ext_vector_type(4)));
typedef float    f32x4 __attribute__((ext_vector_type(4)));

static __device__ __forceinline__ float sigm(float x) {
    return 1.0f / (1.0f + expf(-x));
}

// ---------------------------------------------------------------------------
__global__ void zero_ws(int4* __restrict__ p, int n) {
    int i = blockIdx.x * blockDim.x + threadIdx.x;
    if (i < n) p[i] = int4{0, 0, 0, 0};
}
__global__ void init_pred(const int* __restrict__ tgt, int* __restrict__ pred) {
    int i = blockIdx.x * blockDim.x + threadIdx.x;
    if (i < B_) pred[i] = tgt[i * T_];
}

// ---------------------------------------------------------------------------
// Split 6 weight matrices (fp32 GxD) into fp16 hi/lo planes, gate-interleaved
// column order n' = d*4 + g, MFMA B-frag tile order:
// tile(NI=n'>>4, KC=k>>5), lane = (n'&15) | (((k>>3)&3)<<4), elem = k&7.
// ---------------------------------------------------------------------------
__global__ void split_weights(const float* __restrict__ s0, const float* __restrict__ s1,
                              const float* __restrict__ s2, const float* __restrict__ s3,
                              const float* __restrict__ s4, const float* __restrict__ s5,
                              _Float16* __restrict__ Wbase) {
    int g = blockIdx.x * blockDim.x + threadIdx.x;   // 6 * 2048 * 64
    int mat = g >> 17;
    int rem = g & 131071;
    int np  = rem >> 6;
    int kq  = rem & 63;                               // k-octet
    const float* src = (mat == 0) ? s0 : (mat == 1) ? s1 : (mat == 2) ? s2
                     : (mat == 3) ? s3 : (mat == 4) ? s4 : s5;
    int n = (np & 3) * D_ + (np >> 2);
    const float* sp = src + (size_t)n * D_ + kq * 8;
    float4 v0 = ((const float4*)sp)[0], v1 = ((const float4*)sp)[1];
    float x[8] = {v0.x, v0.y, v0.z, v0.w, v1.x, v1.y, v1.z, v1.w};
    _Float16 hi[8], lo[8];
    #pragma unroll
    for (int u = 0; u < 8; ++u) {
        hi[u] = (_Float16)x[u];
        lo[u] = (_Float16)(x[u] - (float)hi[u]);
    }
    int tile = (np >> 4) * 16 + (kq >> 2);
    int lane = (np & 15) | ((kq & 3) << 4);
    size_t e = (size_t)tile * 512 + (size_t)lane * 8;
    _Float16* Whi = Wbase + (size_t)mat * (2 * LWE);
    _Float16* Wlo = Whi + LWE;
    *(half8*)(Whi + e) = *(half8*)hi;
    *(half8*)(Wlo + e) = *(half8*)lo;
}

// ---------------------------------------------------------------------------
// post_W (80 x 512 fp32) -> hi/lo fp16 B-frag tiles, n' = v.
// ---------------------------------------------------------------------------
__global__ void split_postW(const float* __restrict__ pw,
                            _Float16* __restrict__ Ph, _Float16* __restrict__ Pl) {
    int g = blockIdx.x * blockDim.x + threadIdx.x;   // 80*64 = 5120
    if (g >= VT_ * 64) return;
    int v = g >> 6, kq = g & 63;
    const float* sp = pw + (size_t)v * D_ + kq * 8;
    float4 v0 = ((const float4*)sp)[0], v1 = ((const float4*)sp)[1];
    float x[8] = {v0.x, v0.y, v0.z, v0.w, v1.x, v1.y, v1.z, v1.w};
    _Float16 hi[8], lo[8];
    #pragma unroll
    for (int u = 0; u < 8; ++u) {
        hi[u] = (_Float16)x[u];
        lo[u] = (_Float16)(x[u] - (float)hi[u]);
    }
    int tile = (v >> 4) * 16 + (kq >> 2);
    int lane = (v & 15) | ((kq & 3) << 4);
    size_t e = (size_t)tile * 512 + (size_t)lane * 8;
    *(half8*)(Ph + e) = *(half8*)hi;
    *(half8*)(Pl + e) = *(half8*)lo;
}

// ---------------------------------------------------------------------------
__global__ void perm_bias(const float* __restrict__ ebih, const float* __restrict__ ebhh,
                          const float* __restrict__ dbih, const float* __restrict__ dbhh,
                          float* __restrict__ biasP) {
    int i = blockIdx.x * blockDim.x + threadIdx.x;   // 0..8191
    int cfg = i >> 11, np = i & 2047;
    int n = (np & 3) * D_ + (np >> 2);
    const float* bi = ((cfg < 2) ? ebih : dbih) + (cfg & 1) * G_;
    const float* bh = ((cfg < 2) ? ebhh : dbhh) + (cfg & 1) * G_;
    biasP[cfg * G_ + np] = bi[n] + bh[n];
}

// ---------------------------------------------------------------------------
// Exact fp32 input projections, permuted n'. 18 row-groups of 10 rows.
// ---------------------------------------------------------------------------
__global__ __launch_bounds__(256) void compute_P(
    const float* __restrict__ enc_emb, const float* __restrict__ dec_emb,
    const float* __restrict__ encW0,   const float* __restrict__ decW0,
    float* __restrict__ P) {
    __shared__ float es[10][D_];
    __shared__ float part[4][64][10];
    int by = blockIdx.y;
    bool enc = (by < 10);
    int r0 = enc ? by * 10 : 100 + (by - 10) * 10;
    int s0 = enc ? by * 10 : (by - 10) * 10;
    const float* emb = enc ? enc_emb : dec_emb;
    const float* W   = enc ? encW0 : decW0;
    int tid = threadIdx.x;
    #pragma unroll
    for (int it = 0; it < 5; ++it) {
        int i4 = it * 256 + tid;
        int rr = i4 >> 7, cc = i4 & 127;
        ((float4*)es[rr])[cc] = ((const float4*)(emb + (size_t)(s0 + rr) * D_))[cc];
    }
    __syncthreads();
    int o   = tid & 63;
    int seg = tid >> 6;
    int np = blockIdx.x * 64 + o;
    int n = (np & 3) * D_ + (np >> 2);
    const float* wr = W + (size_t)n * D_ + seg * 128;
    float acc[10];
    #pragma unroll
    for (int rr = 0; rr < 10; ++rr) acc[rr] = 0.f;
    for (int k = 0; k < 128; k += 4) {
        float4 w4 = *(const float4*)(wr + k);
        int kb = seg * 128 + k;
        #pragma unroll
        for (int rr = 0; rr < 10; ++rr)
            acc[rr] += es[rr][kb] * w4.x + es[rr][kb+1] * w4.y
                     + es[rr][kb+2] * w4.z + es[rr][kb+3] * w4.w;
    }
    #pragma unroll
    for (int rr = 0; rr < 10; ++rr) part[seg][o][rr] = acc[rr];
    __syncthreads();
    for (int i = tid; i < 640; i += 256) {
        int o2 = i & 63, rr = i >> 6;
        P[(size_t)(r0 + rr) * G_ + blockIdx.x * 64 + o2] =
            (part[0][o2][rr] + part[1][o2][rr]) + (part[2][o2][rr] + part[3][o2][rr]);
    }
}

// ---------------------------------------------------------------------------
// chunk loaders / MFMA
// ---------------------------------------------------------------------------
static __device__ __forceinline__ void load_chunk(
    const _Float16* __restrict__ Ah, const _Float16* __restrict__ Al,
    const _Float16* __restrict__ Wh, const _Float16* __restrict__ Wl,
    int afr, int wfr, int kc, int lane, half8* A8, half8* B8) {
    size_t lo8 = (size_t)lane * 8;
    #pragma unroll
    for (int i = 0; i < 4; ++i) {
        size_t off = (((size_t)(afr + i) * 16 + kc) << 9) + lo8;
        A8[i]     = *(const half8*)(Ah + off);
        A8[4 + i] = *(const half8*)(Al + off);
    }
    #pragma unroll
    for (int j = 0; j < 4; ++j) {
        size_t off = (((size_t)(wfr + j) * 16 + kc) << 9) + lo8;
        B8[j]     = *(const half8*)(Wh + off);
        B8[4 + j] = *(const half8*)(Wl + off);
    }
}
static __device__ __forceinline__ void mfma_chunk(
    const half8* A8, const half8* B8, f32x4 acc[4][4]) {
    #pragma unroll
    for (int i = 0; i < 4; ++i)
        #pragma unroll
        for (int j = 0; j < 4; ++j) {
            acc[i][j] = __builtin_amdgcn_mfma_f32_16x16x32_f16(A8[i], B8[j], acc[i][j], 0, 0, 0);
            acc[i][j] = __builtin_amdgcn_mfma_f32_16x16x32_f16(A8[i], B8[4 + j], acc[i][j], 0, 0, 0);
            acc[i][j] = __builtin_amdgcn_mfma_f32_16x16x32_f16(A8[4 + i], B8[j], acc[i][j], 0, 0, 0);
        }
}

// ---------------------------------------------------------------------------
// MFMA LSTM cell (R7 shape + XCD swizzle). Block = 512 thr = 8 waves =
// 4 m-waves x 2 K-groups. BM=256, BN'=64. Grid: 1D 256 blocks per job
// (z selects job for encoder pairing). Block decode: m_tile = id & 7,
// n_tile = id >> 3 -- under round-robin XCD assignment (XCD = id % 8) all
// 32 blocks sharing one A-chunk (512 KB) land on ONE XCD's L2 -> A filled
// once per XCD, reused 32x (R8 showed ~3.5x L2 over-fill without this).
// ---------------------------------------------------------------------------
struct CellJob {
    const _Float16 *a0h, *a0l, *w0h, *w0l;
    int kclo0, kchi0;
    const _Float16 *a1h, *a1l, *w1h, *w1l;
    int kclo1, kchi1;
    const float *biasP;
    const float *P;          // permuted input-projection rows, or nullptr
    const int  *idx;
    int idx_stride, emb_rows;
    float *c_io;
    _Float16 *hh_out, *hl_out;
};

__global__ __launch_bounds__(512, 2) void lstm_cell_mfma(CellJob J0, CellJob J1) {
    const CellJob J = (blockIdx.z == 0) ? J0 : J1;
    __shared__ float gf[128][68];
    const int tid  = threadIdx.x;
    const int w    = tid >> 6;
    const int lane = tid & 63;
    const int g    = w >> 2;        // K-group
    const int mw   = w & 3;         // m-wave within group
    const int id   = blockIdx.x;    // 0..255
    const int bx   = id >> 3;       // n'-tile 0..31
    const int m0   = (id & 7) * 256;// m-tile: XCD-local A sharing

    const _Float16* Ah = g ? J.a1h : J.a0h;
    const _Float16* Al = g ? J.a1l : J.a0l;
    const _Float16* Wh = g ? J.w1h : J.w0h;
    const _Float16* Wl = g ? J.w1l : J.w0l;
    const int kclo = g ? J.kclo1 : J.kclo0;
    const int kchi = g ? J.kchi1 : J.kchi0;

    const int afr = (m0 >> 4) + mw * 4;
    const int wfr = bx * 4;

    f32x4 acc[4][4];
    #pragma unroll
    for (int i = 0; i < 4; ++i)
        #pragma unroll
        for (int j = 0; j < 4; ++j) acc[i][j] = f32x4{0.f, 0.f, 0.f, 0.f};

    half8 A0[8], B0[8], A1[8], B1[8];
    load_chunk(Ah, Al, Wh, Wl, afr, wfr, kclo, lane, A0, B0);
    for (int kc = kclo; kc < kchi; kc += 2) {
        load_chunk(Ah, Al, Wh, Wl, afr, wfr, kc + 1, lane, A1, B1);
        mfma_chunk(A0, B0, acc);
        if (kc + 2 < kchi)
            load_chunk(Ah, Al, Wh, Wl, afr, wfr, kc + 2, lane, A0, B0);
        mfma_chunk(A1, B1, acc);
    }

    // ---- epilogue: two passes of 128 m-rows; group-0 writes, group-1 adds ----
    const int rbase = (lane >> 4) << 2;
    const int cbase = lane & 15;
    for (int p = 0; p < 2; ++p) {
        if (g == 0 && (mw >> 1) == p) {
            #pragma unroll
            for (int i = 0; i < 4; ++i) {
                int mrow = (mw & 1) * 64 + i * 16 + rbase;
                #pragma unroll
                for (int j = 0; j < 4; ++j) {
                    int nc = j * 16 + cbase;
                    #pragma unroll
                    for (int r = 0; r < 4; ++r)
                        gf[mrow + r][nc] = acc[i][j][r];
                }
            }
        }
        __syncthreads();
        if (g == 1 && (mw >> 1) == p) {
            #pragma unroll
            for (int i = 0; i < 4; ++i) {
                int mrow = (mw & 1) * 64 + i * 16 + rbase;
                #pragma unroll
                for (int j = 0; j < 4; ++j) {
                    int nc = j * 16 + cbase;
                    #pragma unroll
                    for (int r = 0; r < 4; ++r)
                        gf[mrow + r][nc] += acc[i][j][r];
                }
            }
        }
        __syncthreads();
        {
            int mr = tid >> 2, q = tid & 3;
            int mg = m0 + p * 128 + mr;
            const float4* brow = (const float4*)(J.biasP + (bx << 6));
            const float4* Pr = nullptr;
            if (J.P) {
                int s = J.idx[mg * J.idx_stride];
                s = min(max(s, 0), J.emb_rows - 1);
                Pr = (const float4*)(J.P + (size_t)s * G_ + (bx << 6));
            }
            float* crow = J.c_io + (size_t)mg * D_ + (bx << 4) + (q << 2);
            float4 cv = *(float4*)crow;
            _Float16 hh4[4], hl4[4];
            #pragma unroll
            for (int e = 0; e < 4; ++e) {
                int dl = (q << 2) + e;
                float4 g4 = *(float4*)&gf[mr][dl << 2];
                float4 b4 = brow[dl];
                float gi = g4.x + b4.x, gF = g4.y + b4.y;
                float gg = g4.z + b4.z, go = g4.w + b4.w;
                if (Pr) {
                    float4 p4 = Pr[dl];
                    gi += p4.x; gF += p4.y; gg += p4.z; go += p4.w;
                }
                float cc = (&cv.x)[e];
                float cn = sigm(gF) * cc + sigm(gi) * tanhf(gg);
                float hn = sigm(go) * tanhf(cn);
                (&cv.x)[e] = cn;
                _Float16 hH = (_Float16)hn;
                hh4[e] = hH;
                hl4[e] = (_Float16)(hn - (float)hH);
            }
            *(float4*)crow = cv;
            int kk = (bx << 4) + (q << 2);
            size_t hoff = ((size_t)((mg >> 4) * 16 + (kk >> 5)) << 9)
                        + (size_t)((mg & 15) | (((kk >> 3) & 3) << 4)) * 8
                        + ((q & 1) << 2);
            *(half4_t*)(J.hh_out + hoff) = *(half4_t*)hh4;
            *(half4_t*)(J.hl_out + hoff) = *(half4_t*)hl4;
        }
        __syncthreads();
    }
}

// ---------------------------------------------------------------------------
// MFMA logits + argmax. Grid 32 blocks x 128 thr (2 waves = 2 K-halves).
// ---------------------------------------------------------------------------
__global__ __launch_bounds__(128) void logits_mfma(
    const _Float16* __restrict__ Ah, const _Float16* __restrict__ Al,
    const _Float16* __restrict__ Bh, const _Float16* __restrict__ Bl,
    const float* __restrict__ postb, float* __restrict__ out,
    int t, int* __restrict__ pred) {
    __shared__ float gf2[64][85];
    __shared__ float pb[VT_];
    const int tid = threadIdx.x;
    const int w = tid >> 6;
    const int lane = tid & 63;
    const int m0 = blockIdx.x * 64;
    const int afr = blockIdx.x * 4;

    f32x4 acc[4][5];
    #pragma unroll
    for (int i = 0; i < 4; ++i)
        #pragma unroll
        for (int j = 0; j < 5; ++j) acc[i][j] = f32x4{0.f, 0.f, 0.f, 0.f};

    size_t lo8 = (size_t)lane * 8;
    for (int kc = w * 8; kc < w * 8 + 8; ++kc) {
        half8 A8[8], Bh8[5], Bl8[5];
        #pragma unroll
        for (int i = 0; i < 4; ++i) {
            size_t off = (((size_t)(afr + i) * 16 + kc) << 9) + lo8;
            A8[i]     = *(const half8*)(Ah + off);
            A8[4 + i] = *(const half8*)(Al + off);
        }
        #pragma unroll
        for (int j = 0; j < 5; ++j) {
            size_t off = (((size_t)(j * 16 + kc)) << 9) + lo8;
            Bh8[j] = *(const half8*)(Bh + off);
            Bl8[j] = *(const half8*)(Bl + off);
        }
        #pragma unroll
        for (int i = 0; i < 4; ++i)
            #pragma unroll
            for (int j = 0; j < 5; ++j) {
                acc[i][j] = __builtin_amdgcn_mfma_f32_16x16x32_f16(A8[i], Bh8[j], acc[i][j], 0, 0, 0);
                acc[i][j] = __builtin_amdgcn_mfma_f32_16x16x32_f16(A8[i], Bl8[j], acc[i][j], 0, 0, 0);
                acc[i][j] = __builtin_amdgcn_mfma_f32_16x16x32_f16(A8[4 + i], Bh8[j], acc[i][j], 0, 0, 0);
            }
    }

    if (tid < VT_) pb[tid] = postb[tid];
    const int quad = lane >> 4, c = lane & 15;
    if (w == 0) {
        #pragma unroll
        for (int i = 0; i < 4; ++i)
            #pragma unroll
            for (int j = 0; j < 5; ++j)
                #pragma unroll
                for (int r = 0; r < 4; ++r)
                    gf2[i * 16 + quad * 4 + r][j * 16 + c] = acc[i][j][r];
    }
    __syncthreads();
    if (w == 1) {
        #pragma unroll
        for (int i = 0; i < 4; ++i)
            #pragma unroll
            for (int j = 0; j < 5; ++j)
                #pragma unroll
                for (int r = 0; r < 4; ++r)
                    gf2[i * 16 + quad * 4 + r][j * 16 + c] += acc[i][j][r];
    }
    __syncthreads();
    if (tid < 64) {
        int r = tid;
        float best = -3.4e38f; int bi = 0;
        #pragma unroll
        for (int v = 0; v < VT_; ++v) {
            float x = gf2[r][v] + pb[v];
            if (x > best) { best = x; bi = v; }
        }
        pred[m0 + r] = bi;
        float* orow = out + (size_t)(m0 + r) * (T_ * VT_) + (size_t)t * VT_;
        #pragma unroll
        for (int v4 = 0; v4 < VT_ / 4; ++v4) {
            float4 g4 = *(float4*)&gf2[r][v4 * 4];
            float4 b4 = *(float4*)&pb[v4 * 4];
            float4 o4 = {g4.x + b4.x, g4.y + b4.y, g4.z + b4.z, g4.w + b4.w};
            *(float4*)(orow + v4 * 4) = o4;
        }
    }
}

// ---------------------------------------------------------------------------
extern "C" void kernel_launch(void* const* d_in, const int* in_sizes, int n_in,
                              void* d_out, int out_size, void* d_ws, size_t ws_size,
                              hipStream_t stream) {
    (void)in_sizes; (void)n_in; (void)out_size; (void)ws_size;

    const int*   src     = (const int*)d_in[0];
    const int*   tgt     = (const int*)d_in[1];
    const float* enc_emb = (const float*)d_in[2];
    const float* dec_emb = (const float*)d_in[3];
    const float* enc_Wih = (const float*)d_in[4];
    const float* enc_Whh = (const float*)d_in[5];
    const float* enc_bih = (const float*)d_in[6];
    const float* enc_bhh = (const float*)d_in[7];
    const float* dec_Wih = (const float*)d_in[8];
    const float* dec_Whh = (const float*)d_in[9];
    const float* dec_bih = (const float*)d_in[10];
    const float* dec_bhh = (const float*)d_in[11];
    const float* post_W  = (const float*)d_in[12];
    const float* post_b  = (const float*)d_in[13];

    // ---- ws layout (~50 MiB) ----
    char* wsb = (char*)d_ws;
    int*   pred  = (int*)wsb;                                   // 16 KB
    float* biasB = (float*)(wsb + 16384);                       // 32 KB
    float* Ptab  = (float*)(wsb + 16384 + 32768);               // 1.41 MiB
    char*  zbase = wsb + 16384 + 32768 + 180 * G_ * 4;          // zero-span
    float* C0 = (float*)zbase;
    float* C1 = C0 + BD;
    _Float16* Hh00 = (_Float16*)(C1 + BD);
    _Float16* Hh10 = Hh00 + BD;
    _Float16* Hl00 = Hh10 + BD;
    _Float16* Hl10 = Hl00 + BD;
    _Float16* Hh01 = Hl10 + BD;   // not zeroed (fully written before read)
    _Float16* Hh11 = Hh01 + BD;
    _Float16* Hl01 = Hh11 + BD;
    _Float16* Hl11 = Hl01 + BD;
    _Float16* Wb   = Hl11 + BD;                      // 6 split matrices, 24 MiB
    _Float16* PwH  = Wb + 6 * 2 * LWE;               // post_W hi frag tiles
    _Float16* PwL  = PwH + (size_t)VT_ * D_;         // post_W lo frag tiles

    _Float16* Hhi[2][2] = { { Hh00, Hh01 }, { Hh10, Hh11 } };
    _Float16* Hlo[2][2] = { { Hl00, Hl01 }, { Hl10, Hl11 } };
    float*    Cp[2]     = { C0, C1 };
    auto WP = [&](int m, int pl) { return Wb + (size_t)m * (2 * LWE) + (size_t)pl * LWE; };

    float* out = (float*)d_out;

    // ---- precompute ----
    zero_ws<<<4096, 256, 0, stream>>>((int4*)zbase, (16 * 1024 * 1024) / 16);
    init_pred<<<8, 256, 0, stream>>>(tgt, pred);
    split_weights<<<3072, 256, 0, stream>>>(
        enc_Whh, enc_Wih + LWE, enc_Whh + LWE,
        dec_Whh, dec_Wih + LWE, dec_Whh + LWE, Wb);
    split_postW<<<20, 256, 0, stream>>>(post_W, PwH, PwL);
    perm_bias<<<32, 256, 0, stream>>>(enc_bih, enc_bhh, dec_bih, dec_bhh, biasB);
    {
        dim3 gP(32, 18);
        compute_P<<<gP, 256, 0, stream>>>(enc_emb, dec_emb, enc_Wih, dec_Wih, Ptab);
    }

    dim3 grid1(256, 1, 1);    // single job, 1D swizzled
    dim3 grid2(256, 1, 2);    // paired jobs
    int c0 = 0, c1 = 0;

    auto mkL0 = [&](bool enc, const int* ix, int stride, int rows) {
        int m = enc ? 0 : 3;
        CellJob j;
        j.a0h = Hhi[0][c0]; j.a0l = Hlo[0][c0];
        j.w0h = WP(m, 0);   j.w0l = WP(m, 1);
        j.kclo0 = 0; j.kchi0 = 8;
        j.a1h = Hhi[0][c0]; j.a1l = Hlo[0][c0];
        j.w1h = WP(m, 0);   j.w1l = WP(m, 1);
        j.kclo1 = 8; j.kchi1 = 16;
        j.biasP = biasB + (enc ? 0 : 2) * G_;
        j.P = enc ? Ptab : Ptab + (size_t)100 * G_;
        j.idx = ix; j.idx_stride = stride; j.emb_rows = rows;
        j.c_io = Cp[0];
        j.hh_out = Hhi[0][c0 ^ 1]; j.hl_out = Hlo[0][c0 ^ 1];
        return j;
    };
    auto mkL1 = [&](bool enc) {
        int mi = enc ? 1 : 4, mh = enc ? 2 : 5;
        CellJob j;
        j.a0h = Hhi[0][c0]; j.a0l = Hlo[0][c0];
        j.w0h = WP(mi, 0);  j.w0l = WP(mi, 1);
        j.kclo0 = 0; j.kchi0 = 16;
        j.a1h = Hhi[1][c1]; j.a1l = Hlo[1][c1];
        j.w1h = WP(mh, 0);  j.w1l = WP(mh, 1);
        j.kclo1 = 0; j.kchi1 = 16;
        j.biasP = biasB + (enc ? 1 : 3) * G_;
        j.P = nullptr; j.idx = nullptr; j.idx_stride = 0; j.emb_rows = 0;
        j.c_io = Cp[1];
        j.hh_out = Hhi[1][c1 ^ 1]; j.hl_out = Hlo[1][c1 ^ 1];
        return j;
    };

    // -------- encoder (layer1(t) paired with layer0(t+1)) --------
    {
        CellJob j0 = mkL0(true, src + 0, T_, 100);
        lstm_cell_mfma<<<grid1, 512, 0, stream>>>(j0, j0);
        c0 ^= 1;
        for (int t = 0; t < T_ - 1; ++t) {
            CellJob jA = mkL1(true);                       // layer1(t)
            CellJob jB = mkL0(true, src + t + 1, T_, 100); // layer0(t+1)
            lstm_cell_mfma<<<grid2, 512, 0, stream>>>(jA, jB);
            c1 ^= 1; c0 ^= 1;
        }
        CellJob jZ = mkL1(true);
        lstm_cell_mfma<<<grid1, 512, 0, stream>>>(jZ, jZ);
        c1 ^= 1;
    }

    // -------- decoder (greedy feedback, serial) --------
    for (int t = 0; t < T_; ++t) {
        CellJob j0 = mkL0(false, pred, 1, VT_);
        lstm_cell_mfma<<<grid1, 512, 0, stream>>>(j0, j0);
        c0 ^= 1;
        CellJob j1 = mkL1(false);
        lstm_cell_mfma<<<grid1, 512, 0, stream>>>(j1, j1);
        c1 ^= 1;
        logits_mfma<<<32, 128, 0, stream>>>(
            Hhi[1][c1], Hlo[1][c1], PwH, PwL, post_b, out, t, pred);
    }
}